// Round 4
// baseline (7342.056 us; speedup 1.0000x reference)
//
#include <hip/hip_runtime.h>
#include <cstddef>

#define BB 256   // batch
#define TT 4096  // time steps
#define HH 64    // hidden
#define NT 512   // threads: 64 units x 8 K-slices
#define CH 16    // chunk depth (steps)
#define NCH (TT / CH)

// smem float layout (bank-tuned):
//   [8, 2056)    xc: 2 bufs x 16 rows x 64 cols  (base ≡ 8 mod 32)
//   [2064, 3088) hist ring: 16 rows x 64         (base ≡ 16 mod 32)
#define XC0   8
#define HIST0 2064
#define SMEMF 3092

#define LOG2E  1.442695041f
#define LOG2E2 2.885390082f

// pin a float4's components into arch VGPRs; blocks remat/AGPR-homing
#define PIN4(v) asm volatile("" : "+v"((v).x), "+v"((v).y), "+v"((v).z), "+v"((v).w))

__device__ __forceinline__ float dpp_xor1(float x) {  // lane ^= 1 (quad_perm)
    return __int_as_float(__builtin_amdgcn_mov_dpp(__float_as_int(x), 0xB1, 0xF, 0xF, true));
}
__device__ __forceinline__ float dpp_xor2(float x) {  // lane ^= 2 (quad_perm)
    return __int_as_float(__builtin_amdgcn_mov_dpp(__float_as_int(x), 0x4E, 0xF, 0xF, true));
}
__device__ __forceinline__ float swz_xor4(float x) {  // lane ^= 4 (ds_swizzle)
    return __int_as_float(__builtin_amdgcn_ds_swizzle(__float_as_int(x), 0x101F));
}
__device__ __forceinline__ float frcp(float x) { return __builtin_amdgcn_rcpf(x); }

__device__ __forceinline__ void fma4(float& acc, const float4 w, const float4 x) {
    acc = fmaf(w.x, x.x, acc);
    acc = fmaf(w.y, x.y, acc);
    acc = fmaf(w.z, x.z, acc);
    acc = fmaf(w.w, x.w, acc);
}

// Thread (j = tid>>3, e = tid&7): partials of unit j's 4 gate rows over
// K-slice e (e<4: h cols [16e,+16); e>=4: x cols [16(e-4),+16)). Weights are
// PRE-SCALED by log2e (2*log2e for the tanh gate q==2) so activations use
// native exp2. Reduce via 2 DPP + 1 ds_swizzle; one activation per lane;
// 3-DPP gather; replicated c/h update. Fully unrolled 16-step chunks.
template <bool FIRST, bool LAST>
__global__ __launch_bounds__(NT, 2)
void lstm_layer(const float* __restrict__ xg,   // FIRST: x [B][T][6]
                const float* __restrict__ Wih,  // [256][6] or [256][64]
                const float* __restrict__ Whh,  // [256][64]
                const float* __restrict__ bih,  // [256]
                const float* __restrict__ bhh,  // [256]
                float* __restrict__ seq)        // [T][B][64]
{
    const int b   = blockIdx.x;
    const int tid = threadIdx.x;
    const int j   = tid >> 3;
    const int e   = tid & 7;
    const int eq  = e & 3;
    const int kb  = e >> 2;
    const bool qb0 = (e & 1) != 0;
    const bool qb1 = (e & 2) != 0;

    __shared__ __align__(16) float smem[SMEMF];

    // ---- weights: 16 float4 = 64 floats, arch-VGPR-resident (pinned) ----
    float4 w[4][4];
#pragma unroll
    for (int q = 0; q < 4; ++q)
#pragma unroll
        for (int m = 0; m < 4; ++m) w[q][m] = make_float4(0.f, 0.f, 0.f, 0.f);

    if (!FIRST || kb == 0) {
        const float* Wp = kb ? Wih : Whh;
#pragma unroll
        for (int q = 0; q < 4; ++q) {
            const float ksc = (q == 2) ? LOG2E2 : LOG2E;
            const float4* rp = (const float4*)(Wp + ((q << 6) + j) * HH + eq * 16);
#pragma unroll
            for (int m = 0; m < 4; ++m) {
                float4 v = rp[m];
                w[q][m] = make_float4(v.x * ksc, v.y * ksc, v.z * ksc, v.w * ksc);
            }
        }
    } else if (e == 4) {  // FIRST, x-slice lane: 6-wide rows zero-padded
#pragma unroll
        for (int q = 0; q < 4; ++q) {
            const float ksc = (q == 2) ? LOG2E2 : LOG2E;
            const float* rp = Wih + ((q << 6) + j) * 6;
            w[q][0] = make_float4(rp[0] * ksc, rp[1] * ksc, rp[2] * ksc, rp[3] * ksc);
            w[q][1].x = rp[4] * ksc; w[q][1].y = rp[5] * ksc;
        }
    }
#pragma unroll
    for (int q = 0; q < 4; ++q) {
        PIN4(w[q][0]); PIN4(w[q][1]); PIN4(w[q][2]); PIN4(w[q][3]);
    }

    const int rr = (eq << 6) + j;
    const float kscq = (eq == 2) ? LOG2E2 : LOG2E;
    float biasq = (bih[rr] + bhh[rr]) * kscq;
    const float sg = (eq == 2) ? 2.f : 1.f;   // outer: tanh = 2*s-1
    const float og = (eq == 2) ? -1.f : 0.f;
    asm volatile("" : "+v"(biasq));

    // zero hist (h(-1)=0); FIRST also zeros xc (cols >=6 stay 0 forever)
    if (FIRST) { for (int i = tid; i < SMEMF; i += NT) smem[i] = 0.f; }
    else       { for (int i = HIST0 + tid; i < SMEMF; i += NT) smem[i] = 0.f; }
    __syncthreads();

    // ---- stage chunk 0 ----
    const int srow = tid >> 5;           // 0..15
    const int sc2  = (tid & 31) << 1;    // even col
    const float* gp = nullptr;
    const float* xp = nullptr;
    if (!FIRST) {
        gp = seq + ((size_t)srow * BB + b) * HH + sc2;
        float2 v = *(const float2*)gp;
        *(float2*)&smem[XC0 + srow * 64 + sc2] = v;
        gp += (size_t)CH * BB * HH;      // -> chunk 1
    } else {
        xp = xg + (size_t)b * TT * 6 + tid * 4;
        if (tid < 24) {
            float4 v = *(const float4*)xp;
            float tmp[4] = {v.x, v.y, v.z, v.w};
#pragma unroll
            for (int m = 0; m < 4; ++m) {
                int idx = tid * 4 + m;
                smem[XC0 + (idx / 6) * 64 + (idx % 6)] = tmp[m];
            }
        }
        xp += 96;
    }
    float* sp = seq + ((size_t)srow * BB + b) * HH + sc2;   // flush ptr
    float c = 0.f;
    __syncthreads();

    float2 pf2 = make_float2(0.f, 0.f);
    float4 pf4 = make_float4(0.f, 0.f, 0.f, 0.f);

    for (int ck = 0; ck < NCH; ++ck) {
        // re-assert residency each chunk (empty asm, no code)
#pragma unroll
        for (int q = 0; q < 4; ++q) {
            PIN4(w[q][0]); PIN4(w[q][1]); PIN4(w[q][2]); PIN4(w[q][3]);
        }
        asm volatile("" : "+v"(biasq));

        const int buf = ck & 1;
        const float* vb  = kb ? (smem + XC0 + buf * 1024 + eq * 16)
                              : (smem + HIST0 - 64 + eq * 16);
        const float* vb0 = kb ? vb : (smem + HIST0 + 15 * 64 + eq * 16);
        const bool pfv = (ck + 1 < NCH);

#pragma unroll
        for (int ph = 0; ph < CH; ++ph) {
            if (ph == 0 && pfv) {   // issue next-chunk global loads early
                if (!FIRST) pf2 = *(const float2*)gp;
                else if (tid < 24) pf4 = *(const float4*)xp;
            }

            const float4* vp = (const float4*)((ph == 0) ? vb0 : (vb + ph * 64));
            const float4 vv0 = vp[0], vv1 = vp[1], vv2 = vp[2], vv3 = vp[3];

            float a0, a1, a2, a3;
            {
                float pa, pb;
                pa = 0.f; pb = 0.f;
                fma4(pa, w[0][0], vv0); fma4(pb, w[0][1], vv1);
                fma4(pa, w[0][2], vv2); fma4(pb, w[0][3], vv3); a0 = pa + pb;
                pa = 0.f; pb = 0.f;
                fma4(pa, w[1][0], vv0); fma4(pb, w[1][1], vv1);
                fma4(pa, w[1][2], vv2); fma4(pb, w[1][3], vv3); a1 = pa + pb;
                pa = 0.f; pb = 0.f;
                fma4(pa, w[2][0], vv0); fma4(pb, w[2][1], vv1);
                fma4(pa, w[2][2], vv2); fma4(pb, w[2][3], vv3); a2 = pa + pb;
                pa = 0.f; pb = 0.f;
                fma4(pa, w[3][0], vv0); fma4(pb, w[3][1], vv1);
                fma4(pa, w[3][2], vv2); fma4(pb, w[3][3], vv3); a3 = pa + pb;
            }

            // reduce-scatter over e: lane ends with gate q = e&3
            const float s0 = dpp_xor1(a0), s1 = dpp_xor1(a1);
            const float s2 = dpp_xor1(a2), s3 = dpp_xor1(a3);
            const float k0 = qb0 ? (a1 + s1) : (a0 + s0);
            const float k2 = qb0 ? (a3 + s3) : (a2 + s2);
            const float u0 = dpp_xor2(k0), u2 = dpp_xor2(k2);
            float g = qb1 ? (k2 + u2) : (k0 + u0);
            g += swz_xor4(g);
            g += biasq;

            // act: sigm(x)=1/(1+exp2(-x*log2e)) with log2e pre-folded into w/b
            const float act = fmaf(sg, frcp(1.f + exp2f(-g)), og);

            // gather acts, replicated c/h update
            const float v1 = dpp_xor1(act);
            const float v2 = dpp_xor2(act);
            const float v3 = dpp_xor2(v1);
            const float px = act * v2, py = v1 * v3;
            const float P1 = qb0 ? py : px;   // sigm(i)*tanh(g)
            const float A  = qb0 ? act : v1;
            const float Bx = qb0 ? v2 : v3;
            const float fv = qb1 ? Bx : A;    // sigm(f)
            const float ov = qb1 ? A : Bx;    // sigm(o)

            c = fmaf(fv, c, P1);
            const float tc = fmaf(2.f, frcp(1.f + exp2f(c * -LOG2E2)), -1.f);  // tanh(c)
            const float hn = ov * tc;

            if (e == 0) smem[HIST0 + ph * 64 + j] = hn;   // hist[ph] = h(t)

            if (ph == 8 && pfv) {   // land next-chunk stage
                if (!FIRST) {
                    *(float2*)&smem[XC0 + (1 - buf) * 1024 + srow * 64 + sc2] = pf2;
                } else if (tid < 24) {
                    float tmp[4] = {pf4.x, pf4.y, pf4.z, pf4.w};
#pragma unroll
                    for (int m = 0; m < 4; ++m) {
                        int idx = tid * 4 + m;
                        smem[XC0 + (1 - buf) * 1024 + (idx / 6) * 64 + (idx % 6)] = tmp[m];
                    }
                }
            }
            __syncthreads();
        }

        // coalesced flush: hist rows 0..15 -> seq rows ck*16..+15
        if (!LAST) {
            float2 hv = *(const float2*)&smem[HIST0 + srow * 64 + sc2];
            *(float2*)sp = hv;
            __syncthreads();   // protect hist[0] from next chunk's ph0 write
        } else if (ck == NCH - 1) {
            if (srow == 15) {
                float2 hv = *(const float2*)&smem[HIST0 + 15 * 64 + sc2];
                *(float2*)sp = hv;
            }
        }
        sp += (size_t)CH * BB * HH;
        if (!FIRST) gp += (size_t)CH * BB * HH;
        else        xp += 96;
    }
}

// out[b] = fc_b + sum_j relu(h[T-1][b][j]) * fc_w[j]
__global__ __launch_bounds__(256)
void fc_kernel(const float* __restrict__ seq, const float* __restrict__ fcw,
               const float* __restrict__ fcb, float* __restrict__ out)
{
    __shared__ float w[HH];
    const int tid = threadIdx.x;
    if (tid < HH) w[tid] = fcw[tid];
    __syncthreads();
    const float* h = &seq[((size_t)(TT - 1) * BB + tid) * HH];
    float s = fcb[0];
#pragma unroll
    for (int jj = 0; jj < HH; ++jj)
        s = fmaf(fmaxf(h[jj], 0.f), w[jj], s);
    out[tid] = s;
}

extern "C" void kernel_launch(void* const* d_in, const int* in_sizes, int n_in,
                              void* d_out, int out_size, void* d_ws, size_t ws_size,
                              hipStream_t stream) {
    const float* x    = (const float*)d_in[0];  // [B][T][6]
    const float* Wih0 = (const float*)d_in[1];  // [256][6]
    const float* WihR = (const float*)d_in[2];  // [3][256][64]
    const float* Whh  = (const float*)d_in[3];  // [4][256][64]
    const float* bih  = (const float*)d_in[4];  // [4][256]
    const float* bhh  = (const float*)d_in[5];  // [4][256]
    const float* fcw  = (const float*)d_in[6];  // [1][64]
    const float* fcb  = (const float*)d_in[7];  // [1]
    float* out = (float*)d_out;
    float* seq = (float*)d_ws;                  // [T][B][64] fp32 = 268 MB

    dim3 grid(BB), block(NT);

    lstm_layer<true, false><<<grid, block, 0, stream>>>(x, Wih0, Whh, bih, bhh, seq);
    lstm_layer<false, false><<<grid, block, 0, stream>>>(
        nullptr, WihR + (size_t)0 * 256 * HH, Whh + (size_t)1 * 256 * HH,
        bih + 256, bhh + 256, seq);
    lstm_layer<false, false><<<grid, block, 0, stream>>>(
        nullptr, WihR + (size_t)1 * 256 * HH, Whh + (size_t)2 * 256 * HH,
        bih + 2 * 256, bhh + 2 * 256, seq);
    lstm_layer<false, true><<<grid, block, 0, stream>>>(
        nullptr, WihR + (size_t)2 * 256 * HH, Whh + (size_t)3 * 256 * HH,
        bih + 3 * 256, bhh + 3 * 256, seq);

    fc_kernel<<<dim3(1), dim3(256), 0, stream>>>(seq, fcw, fcb, out);
}

// Round 6
// 7255.193 us; speedup vs baseline: 1.0120x; 1.0120x over previous
//
#include <hip/hip_runtime.h>
#include <cstddef>

#define BB 256   // batch
#define TT 4096  // time steps
#define HH 64    // hidden
#define NT 512   // threads: 64 units x 8 K-slices
#define CH 16    // chunk depth (steps)
#define NCH (TT / CH)

// smem float layout (bank-tuned):
//   [8, 2056)    xc: 2 bufs x 16 rows x 64 cols  (base ≡ 8 mod 32)
//   [2064, 3088) hist ring: 16 rows x 64         (base ≡ 16 mod 32)
#define XC0   8
#define HIST0 2064
#define SMEMF 3092

#define LOG2E  1.442695041f
#define LOG2E2 2.885390082f

__device__ __forceinline__ float dpp_xor1(float x) {  // lane ^= 1 (quad_perm)
    return __int_as_float(__builtin_amdgcn_mov_dpp(__float_as_int(x), 0xB1, 0xF, 0xF, true));
}
__device__ __forceinline__ float dpp_xor2(float x) {  // lane ^= 2 (quad_perm)
    return __int_as_float(__builtin_amdgcn_mov_dpp(__float_as_int(x), 0x4E, 0xF, 0xF, true));
}
__device__ __forceinline__ float swz_xor4(float x) {  // lane ^= 4 (ds_swizzle)
    return __int_as_float(__builtin_amdgcn_ds_swizzle(__float_as_int(x), 0x101F));
}
__device__ __forceinline__ float frcp(float x) { return __builtin_amdgcn_rcpf(x); }

// Thread (j = tid>>3, e = tid&7): partials of unit j's 4 gate rows over
// K-slice e (e<4: h cols [16e,+16); e>=4: x cols [16(e-4),+16)). Weights
// PRE-SCALED by log2e (2*log2e for tanh gate q==2); bias*ksc/8 folded in as
// the first-FMA addend of each gate chain (8-lane reduce tree sums 8 copies
// -> full bias). Reduce via 2 DPP + 1 ds_swizzle; one activation per lane;
// 3-DPP gather; replicated c/h update. Fully unrolled 16-step chunks.
// amdgpu_waves_per_eu(2,2): grid is fixed at 1 block/CU = 2 waves/EU, so cap
// the allocator's occupancy target there -> 256-VGPR budget -> weights live
// in arch VGPRs, no AGPR bounce.
template <bool FIRST, bool LAST>
__global__ __attribute__((amdgpu_flat_work_group_size(NT, NT), amdgpu_waves_per_eu(2, 2)))
void lstm_layer(const float* __restrict__ xg,   // FIRST: x [B][T][6]
                const float* __restrict__ Wih,  // [256][6] or [256][64]
                const float* __restrict__ Whh,  // [256][64]
                const float* __restrict__ bih,  // [256]
                const float* __restrict__ bhh,  // [256]
                float* __restrict__ seq)        // [T][B][64]
{
    const int b   = blockIdx.x;
    const int tid = threadIdx.x;
    const int j   = tid >> 3;
    const int e   = tid & 7;
    const int eq  = e & 3;
    const int kb  = e >> 2;
    const bool qb0 = (e & 1) != 0;
    const bool qb1 = (e & 2) != 0;

    __shared__ __align__(16) float smem[SMEMF];

    // ---- weights: 16 named float4 = 64 floats, arch-VGPR-resident ----
    float4 w00, w01, w02, w03, w10, w11, w12, w13;
    float4 w20, w21, w22, w23, w30, w31, w32, w33;
    {
        const float4 z = make_float4(0.f, 0.f, 0.f, 0.f);
        w00 = z; w01 = z; w02 = z; w03 = z; w10 = z; w11 = z; w12 = z; w13 = z;
        w20 = z; w21 = z; w22 = z; w23 = z; w30 = z; w31 = z; w32 = z; w33 = z;
    }
    if (!FIRST || kb == 0) {
        const float* Wp = kb ? Wih : Whh;
#define LDW(q, KS) { const float4* rp = (const float4*)(Wp + ((q << 6) + j) * HH + eq * 16); \
        float4 v0 = rp[0], v1 = rp[1], v2 = rp[2], v3 = rp[3]; \
        (w##q##0) = make_float4(v0.x*KS, v0.y*KS, v0.z*KS, v0.w*KS); \
        (w##q##1) = make_float4(v1.x*KS, v1.y*KS, v1.z*KS, v1.w*KS); \
        (w##q##2) = make_float4(v2.x*KS, v2.y*KS, v2.z*KS, v2.w*KS); \
        (w##q##3) = make_float4(v3.x*KS, v3.y*KS, v3.z*KS, v3.w*KS); }
        LDW(0, LOG2E) LDW(1, LOG2E) LDW(2, LOG2E2) LDW(3, LOG2E)
#undef LDW
    } else if (e == 4) {  // FIRST, x-slice lane: 6-wide rows zero-padded
#define LDW6(q, KS) { const float* rp = Wih + ((q << 6) + j) * 6; \
        (w##q##0) = make_float4(rp[0]*KS, rp[1]*KS, rp[2]*KS, rp[3]*KS); \
        (w##q##1).x = rp[4]*KS; (w##q##1).y = rp[5]*KS; }
        LDW6(0, LOG2E) LDW6(1, LOG2E) LDW6(2, LOG2E2) LDW6(3, LOG2E)
#undef LDW6
    }

    // per-gate bias * ksc / 8 (8-lane reduce tree sums 8 copies -> full bias)
    const float b0 = (bih[0 * 64 + j] + bhh[0 * 64 + j]) * (LOG2E * 0.125f);
    const float b1 = (bih[1 * 64 + j] + bhh[1 * 64 + j]) * (LOG2E * 0.125f);
    const float b2 = (bih[2 * 64 + j] + bhh[2 * 64 + j]) * (LOG2E2 * 0.125f);
    const float b3 = (bih[3 * 64 + j] + bhh[3 * 64 + j]) * (LOG2E * 0.125f);

    const float sg = (eq == 2) ? 2.f : 1.f;   // outer: tanh = 2*s-1
    const float og = (eq == 2) ? -1.f : 0.f;

    // zero hist (h(-1)=0); FIRST also zeros xc (cols >=6 stay 0 forever)
    if (FIRST) { for (int i = tid; i < SMEMF; i += NT) smem[i] = 0.f; }
    else       { for (int i = HIST0 + tid; i < SMEMF; i += NT) smem[i] = 0.f; }
    __syncthreads();

    // ---- stage chunk 0 ----
    const int srow = tid >> 5;           // 0..15
    const int sc2  = (tid & 31) << 1;    // even col
    const float* gp = nullptr;
    const float* xp = nullptr;
    if (!FIRST) {
        gp = seq + ((size_t)srow * BB + b) * HH + sc2;
        float2 v = *(const float2*)gp;
        *(float2*)&smem[XC0 + srow * 64 + sc2] = v;
        gp += (size_t)CH * BB * HH;      // -> chunk 1
    } else {
        xp = xg + (size_t)b * TT * 6 + tid * 4;
        if (tid < 24) {
            float4 v = *(const float4*)xp;
            float tmp[4] = {v.x, v.y, v.z, v.w};
#pragma unroll
            for (int m = 0; m < 4; ++m) {
                int idx = tid * 4 + m;
                smem[XC0 + (idx / 6) * 64 + (idx % 6)] = tmp[m];
            }
        }
        xp += 96;
    }
    float* sp = seq + ((size_t)srow * BB + b) * HH + sc2;   // flush ptr
    float c = 0.f;
    __syncthreads();

    float2 pf2 = make_float2(0.f, 0.f);
    float4 pf4 = make_float4(0.f, 0.f, 0.f, 0.f);

    for (int ck = 0; ck < NCH; ++ck) {
        const int buf = ck & 1;
        const float* vb  = kb ? (smem + XC0 + buf * 1024 + eq * 16)
                              : (smem + HIST0 - 64 + eq * 16);
        const float* vb0 = kb ? vb : (smem + HIST0 + 15 * 64 + eq * 16);
        const bool pfv = (ck + 1 < NCH);

#pragma unroll
        for (int ph = 0; ph < CH; ++ph) {
            if (ph == 0 && pfv) {   // issue next-chunk global loads early
                if (!FIRST) pf2 = *(const float2*)gp;
                else if (tid < 24) pf4 = *(const float4*)xp;
            }

            const float4* vp = (const float4*)((ph == 0) ? vb0 : (vb + ph * 64));
            const float4 vv0 = vp[0], vv1 = vp[1], vv2 = vp[2], vv3 = vp[3];

            // gate chains: first ops fold bias/8 (fma) and replace zero-init
#define GATE(q, bq, aq) { \
            float pa = fmaf((w##q##0).x, vv0.x, bq); \
            pa = fmaf((w##q##0).y, vv0.y, pa); \
            pa = fmaf((w##q##0).z, vv0.z, pa); \
            pa = fmaf((w##q##0).w, vv0.w, pa); \
            float pb = (w##q##1).x * vv1.x; \
            pb = fmaf((w##q##1).y, vv1.y, pb); \
            pb = fmaf((w##q##1).z, vv1.z, pb); \
            pb = fmaf((w##q##1).w, vv1.w, pb); \
            pa = fmaf((w##q##2).x, vv2.x, pa); \
            pa = fmaf((w##q##2).y, vv2.y, pa); \
            pa = fmaf((w##q##2).z, vv2.z, pa); \
            pa = fmaf((w##q##2).w, vv2.w, pa); \
            pb = fmaf((w##q##3).x, vv3.x, pb); \
            pb = fmaf((w##q##3).y, vv3.y, pb); \
            pb = fmaf((w##q##3).z, vv3.z, pb); \
            pb = fmaf((w##q##3).w, vv3.w, pb); \
            aq = pa + pb; }
            float a0, a1, a2, a3;
            GATE(0, b0, a0) GATE(1, b1, a1) GATE(2, b2, a2) GATE(3, b3, a3)
#undef GATE

            // reduce-scatter over e: lane ends with gate q = e&3
            const float s0 = dpp_xor1(a0), s1 = dpp_xor1(a1);
            const float s2 = dpp_xor1(a2), s3 = dpp_xor1(a3);
            const float k0 = qb0 ? (a1 + s1) : (a0 + s0);
            const float k2 = qb0 ? (a3 + s3) : (a2 + s2);
            const float u0 = dpp_xor2(k0), u2 = dpp_xor2(k2);
            float g = qb1 ? (k2 + u2) : (k0 + u0);
            g += swz_xor4(g);

            // act: sigm via native exp2 (log2e pre-folded into w/b)
            const float act = fmaf(sg, frcp(1.f + exp2f(-g)), og);

            // gather acts, replicated c/h update
            const float v1 = dpp_xor1(act);
            const float v2 = dpp_xor2(act);
            const float v3 = dpp_xor2(v1);
            const float px = act * v2, py = v1 * v3;
            const float P1 = qb0 ? py : px;   // sigm(i)*tanh(g)
            const float A  = qb0 ? act : v1;
            const float Bx = qb0 ? v2 : v3;
            const float fv = qb1 ? Bx : A;    // sigm(f)
            const float ov = qb1 ? A : Bx;    // sigm(o)

            c = fmaf(fv, c, P1);
            const float tc = fmaf(2.f, frcp(1.f + exp2f(c * -LOG2E2)), -1.f);  // tanh(c)
            const float hn = ov * tc;

            if (e == 0) smem[HIST0 + ph * 64 + j] = hn;   // hist[ph] = h(t)

            if (ph == 8 && pfv) {   // land next-chunk stage
                if (!FIRST) {
                    *(float2*)&smem[XC0 + (1 - buf) * 1024 + srow * 64 + sc2] = pf2;
                } else if (tid < 24) {
                    float tmp[4] = {pf4.x, pf4.y, pf4.z, pf4.w};
#pragma unroll
                    for (int m = 0; m < 4; ++m) {
                        int idx = tid * 4 + m;
                        smem[XC0 + (1 - buf) * 1024 + (idx / 6) * 64 + (idx % 6)] = tmp[m];
                    }
                }
            }
            __syncthreads();
        }

        // coalesced flush: hist rows 0..15 -> seq rows ck*16..+15
        if (!LAST) {
            float2 hv = *(const float2*)&smem[HIST0 + srow * 64 + sc2];
            *(float2*)sp = hv;
            __syncthreads();   // protect hist[0] from next chunk's ph0 write
        } else if (ck == NCH - 1) {
            if (srow == 15) {
                float2 hv = *(const float2*)&smem[HIST0 + 15 * 64 + sc2];
                *(float2*)sp = hv;
            }
        }
        sp += (size_t)CH * BB * HH;
        if (!FIRST) gp += (size_t)CH * BB * HH;
        else        xp += 96;
    }
}

// out[b] = fc_b + sum_j relu(h[T-1][b][j]) * fc_w[j]
__global__ __launch_bounds__(256)
void fc_kernel(const float* __restrict__ seq, const float* __restrict__ fcw,
               const float* __restrict__ fcb, float* __restrict__ out)
{
    __shared__ float w[HH];
    const int tid = threadIdx.x;
    if (tid < HH) w[tid] = fcw[tid];
    __syncthreads();
    const float* h = &seq[((size_t)(TT - 1) * BB + tid) * HH];
    float s = fcb[0];
#pragma unroll
    for (int jj = 0; jj < HH; ++jj)
        s = fmaf(fmaxf(h[jj], 0.f), w[jj], s);
    out[tid] = s;
}

extern "C" void kernel_launch(void* const* d_in, const int* in_sizes, int n_in,
                              void* d_out, int out_size, void* d_ws, size_t ws_size,
                              hipStream_t stream) {
    const float* x    = (const float*)d_in[0];  // [B][T][6]
    const float* Wih0 = (const float*)d_in[1];  // [256][6]
    const float* WihR = (const float*)d_in[2];  // [3][256][64]
    const float* Whh  = (const float*)d_in[3];  // [4][256][64]
    const float* bih  = (const float*)d_in[4];  // [4][256]
    const float* bhh  = (const float*)d_in[5];  // [4][256]
    const float* fcw  = (const float*)d_in[6];  // [1][64]
    const float* fcb  = (const float*)d_in[7];  // [1]
    float* out = (float*)d_out;
    float* seq = (float*)d_ws;                  // [T][B][64] fp32 = 268 MB

    dim3 grid(BB), block(NT);

    lstm_layer<true, false><<<grid, block, 0, stream>>>(x, Wih0, Whh, bih, bhh, seq);
    lstm_layer<false, false><<<grid, block, 0, stream>>>(
        nullptr, WihR + (size_t)0 * 256 * HH, Whh + (size_t)1 * 256 * HH,
        bih + 256, bhh + 256, seq);
    lstm_layer<false, false><<<grid, block, 0, stream>>>(
        nullptr, WihR + (size_t)1 * 256 * HH, Whh + (size_t)2 * 256 * HH,
        bih + 2 * 256, bhh + 2 * 256, seq);
    lstm_layer<false, true><<<grid, block, 0, stream>>>(
        nullptr, WihR + (size_t)2 * 256 * HH, Whh + (size_t)3 * 256 * HH,
        bih + 3 * 256, bhh + 3 * 256, seq);

    fc_kernel<<<dim3(1), dim3(256), 0, stream>>>(seq, fcw, fcb, out);
}

// Round 7
// 7245.402 us; speedup vs baseline: 1.0133x; 1.0014x over previous
//
#include <hip/hip_runtime.h>
#include <cstddef>

#define BB 256   // batch
#define TT 4096  // time steps
#define HH 64    // hidden
#define NT 512   // threads: 64 units x 8 K-slices
#define CH 16    // chunk depth (steps)
#define NCH (TT / CH)

// smem float layout (bank-tuned):
//   [8, 2056)    xc: 2 bufs x 16 rows x 64 cols  (base ≡ 8 mod 32)
//   [2064, 3088) hist ring: 16 rows x 64         (base ≡ 16 mod 32)
#define XC0   8
#define HIST0 2064
#define SMEMF 3092

#define LOG2E  1.442695041f
#define LOG2E2 2.885390082f

__device__ __forceinline__ float dpp_xor1(float x) {  // lane ^= 1 (quad_perm)
    return __int_as_float(__builtin_amdgcn_mov_dpp(__float_as_int(x), 0xB1, 0xF, 0xF, true));
}
__device__ __forceinline__ float dpp_xor2(float x) {  // lane ^= 2 (quad_perm)
    return __int_as_float(__builtin_amdgcn_mov_dpp(__float_as_int(x), 0x4E, 0xF, 0xF, true));
}
__device__ __forceinline__ float swz_xor4(float x) {  // lane ^= 4 (ds_swizzle)
    return __int_as_float(__builtin_amdgcn_ds_swizzle(__float_as_int(x), 0x101F));
}
__device__ __forceinline__ float frcp(float x) { return __builtin_amdgcn_rcpf(x); }

// Raw workgroup barrier: LDS-ordering only (s_waitcnt lgkmcnt(0) + s_barrier).
// Unlike __syncthreads, does NOT drain vmcnt — global prefetch loads stay in
// flight across steps (T3/T4 recipe). "memory" clobber orders all LDS ops.
__device__ __forceinline__ void lds_barrier() {
    asm volatile("s_waitcnt lgkmcnt(0)\n\ts_barrier" ::: "memory");
}

// Thread (j = tid>>3, e = tid&7): partials of unit j's 4 gate rows over
// K-slice e (e<4: h cols [16e,+16); e>=4: x cols [16(e-4),+16)). Weights
// PRE-SCALED by log2e (2*log2e for tanh gate q==2); bias*ksc/8 folded in as
// the first-FMA addend of each gate chain (8-lane reduce tree sums 8 copies
// -> full bias). Reduce via 2 DPP + 1 ds_swizzle; one activation per lane;
// 3-DPP gather; replicated c/h update. Fully unrolled 16-step chunks.
// Per-step sync = raw lgkm-only barrier (no vmcnt drain); full __syncthreads
// only at chunk boundaries (ph==15 and after flush).
template <bool FIRST, bool LAST>
__global__ __attribute__((amdgpu_flat_work_group_size(NT, NT), amdgpu_waves_per_eu(2, 2)))
void lstm_layer(const float* __restrict__ xg,   // FIRST: x [B][T][6]
                const float* __restrict__ Wih,  // [256][6] or [256][64]
                const float* __restrict__ Whh,  // [256][64]
                const float* __restrict__ bih,  // [256]
                const float* __restrict__ bhh,  // [256]
                float* __restrict__ seq)        // [T][B][64]
{
    const int b   = blockIdx.x;
    const int tid = threadIdx.x;
    const int j   = tid >> 3;
    const int e   = tid & 7;
    const int eq  = e & 3;
    const int kb  = e >> 2;
    const bool qb0 = (e & 1) != 0;
    const bool qb1 = (e & 2) != 0;

    __shared__ __align__(16) float smem[SMEMF];

    // ---- weights: 16 named float4 = 64 floats ----
    float4 w00, w01, w02, w03, w10, w11, w12, w13;
    float4 w20, w21, w22, w23, w30, w31, w32, w33;
    {
        const float4 z = make_float4(0.f, 0.f, 0.f, 0.f);
        w00 = z; w01 = z; w02 = z; w03 = z; w10 = z; w11 = z; w12 = z; w13 = z;
        w20 = z; w21 = z; w22 = z; w23 = z; w30 = z; w31 = z; w32 = z; w33 = z;
    }
    if (!FIRST || kb == 0) {
        const float* Wp = kb ? Wih : Whh;
#define LDW(q, KS) { const float4* rp = (const float4*)(Wp + ((q << 6) + j) * HH + eq * 16); \
        float4 v0 = rp[0], v1 = rp[1], v2 = rp[2], v3 = rp[3]; \
        (w##q##0) = make_float4(v0.x*KS, v0.y*KS, v0.z*KS, v0.w*KS); \
        (w##q##1) = make_float4(v1.x*KS, v1.y*KS, v1.z*KS, v1.w*KS); \
        (w##q##2) = make_float4(v2.x*KS, v2.y*KS, v2.z*KS, v2.w*KS); \
        (w##q##3) = make_float4(v3.x*KS, v3.y*KS, v3.z*KS, v3.w*KS); }
        LDW(0, LOG2E) LDW(1, LOG2E) LDW(2, LOG2E2) LDW(3, LOG2E)
#undef LDW
    } else if (e == 4) {  // FIRST, x-slice lane: 6-wide rows zero-padded
#define LDW6(q, KS) { const float* rp = Wih + ((q << 6) + j) * 6; \
        (w##q##0) = make_float4(rp[0]*KS, rp[1]*KS, rp[2]*KS, rp[3]*KS); \
        (w##q##1).x = rp[4]*KS; (w##q##1).y = rp[5]*KS; }
        LDW6(0, LOG2E) LDW6(1, LOG2E) LDW6(2, LOG2E2) LDW6(3, LOG2E)
#undef LDW6
    }

    // per-gate bias * ksc / 8 (8-lane reduce tree sums 8 copies -> full bias)
    const float b0 = (bih[0 * 64 + j] + bhh[0 * 64 + j]) * (LOG2E * 0.125f);
    const float b1 = (bih[1 * 64 + j] + bhh[1 * 64 + j]) * (LOG2E * 0.125f);
    const float b2 = (bih[2 * 64 + j] + bhh[2 * 64 + j]) * (LOG2E2 * 0.125f);
    const float b3 = (bih[3 * 64 + j] + bhh[3 * 64 + j]) * (LOG2E * 0.125f);

    const float sg = (eq == 2) ? 2.f : 1.f;   // outer: tanh = 2*s-1
    const float og = (eq == 2) ? -1.f : 0.f;

    // zero hist (h(-1)=0); FIRST also zeros xc (cols >=6 stay 0 forever)
    if (FIRST) { for (int i = tid; i < SMEMF; i += NT) smem[i] = 0.f; }
    else       { for (int i = HIST0 + tid; i < SMEMF; i += NT) smem[i] = 0.f; }
    __syncthreads();

    // ---- stage chunk 0 ----
    const int srow = tid >> 5;           // 0..15
    const int sc2  = (tid & 31) << 1;    // even col
    const float* gp = nullptr;
    const float* xp = nullptr;
    if (!FIRST) {
        gp = seq + ((size_t)srow * BB + b) * HH + sc2;
        float2 v = *(const float2*)gp;
        *(float2*)&smem[XC0 + srow * 64 + sc2] = v;
        gp += (size_t)CH * BB * HH;      // -> chunk 1
    } else {
        xp = xg + (size_t)b * TT * 6 + tid * 4;
        if (tid < 24) {
            float4 v = *(const float4*)xp;
            float tmp[4] = {v.x, v.y, v.z, v.w};
#pragma unroll
            for (int m = 0; m < 4; ++m) {
                int idx = tid * 4 + m;
                smem[XC0 + (idx / 6) * 64 + (idx % 6)] = tmp[m];
            }
        }
        xp += 96;
    }
    float* sp = seq + ((size_t)srow * BB + b) * HH + sc2;   // flush ptr
    float c = 0.f;
    __syncthreads();

    float2 pf2 = make_float2(0.f, 0.f);
    float4 pf4 = make_float4(0.f, 0.f, 0.f, 0.f);

    for (int ck = 0; ck < NCH; ++ck) {
        const int buf = ck & 1;
        const float* vb  = kb ? (smem + XC0 + buf * 1024 + eq * 16)
                              : (smem + HIST0 - 64 + eq * 16);
        const float* vb0 = kb ? vb : (smem + HIST0 + 15 * 64 + eq * 16);
        const bool pfv = (ck + 1 < NCH);

#pragma unroll
        for (int ph = 0; ph < CH; ++ph) {
            if (ph == 0 && pfv) {   // issue next-chunk global loads; they stay
                if (!FIRST) pf2 = *(const float2*)gp;        // in flight across
                else if (tid < 24) pf4 = *(const float4*)xp; // raw barriers
            }

            const float4* vp = (const float4*)((ph == 0) ? vb0 : (vb + ph * 64));
            const float4 vv0 = vp[0], vv1 = vp[1], vv2 = vp[2], vv3 = vp[3];

            // gate chains: first ops fold bias/8 (fma) and replace zero-init
#define GATE(q, bq, aq) { \
            float pa = fmaf((w##q##0).x, vv0.x, bq); \
            pa = fmaf((w##q##0).y, vv0.y, pa); \
            pa = fmaf((w##q##0).z, vv0.z, pa); \
            pa = fmaf((w##q##0).w, vv0.w, pa); \
            float pb = (w##q##1).x * vv1.x; \
            pb = fmaf((w##q##1).y, vv1.y, pb); \
            pb = fmaf((w##q##1).z, vv1.z, pb); \
            pb = fmaf((w##q##1).w, vv1.w, pb); \
            pa = fmaf((w##q##2).x, vv2.x, pa); \
            pa = fmaf((w##q##2).y, vv2.y, pa); \
            pa = fmaf((w##q##2).z, vv2.z, pa); \
            pa = fmaf((w##q##2).w, vv2.w, pa); \
            pb = fmaf((w##q##3).x, vv3.x, pb); \
            pb = fmaf((w##q##3).y, vv3.y, pb); \
            pb = fmaf((w##q##3).z, vv3.z, pb); \
            pb = fmaf((w##q##3).w, vv3.w, pb); \
            aq = pa + pb; }
            float a0, a1, a2, a3;
            GATE(0, b0, a0) GATE(1, b1, a1) GATE(2, b2, a2) GATE(3, b3, a3)
#undef GATE

            // reduce-scatter over e: lane ends with gate q = e&3
            const float s0 = dpp_xor1(a0), s1 = dpp_xor1(a1);
            const float s2 = dpp_xor1(a2), s3 = dpp_xor1(a3);
            const float k0 = qb0 ? (a1 + s1) : (a0 + s0);
            const float k2 = qb0 ? (a3 + s3) : (a2 + s2);
            const float u0 = dpp_xor2(k0), u2 = dpp_xor2(k2);
            float g = qb1 ? (k2 + u2) : (k0 + u0);
            g += swz_xor4(g);

            // act: sigm via native exp2 (log2e pre-folded into w/b)
            const float act = fmaf(sg, frcp(1.f + exp2f(-g)), og);

            // gather acts, replicated c/h update
            const float v1 = dpp_xor1(act);
            const float v2 = dpp_xor2(act);
            const float v3 = dpp_xor2(v1);
            const float px = act * v2, py = v1 * v3;
            const float P1 = qb0 ? py : px;   // sigm(i)*tanh(g)
            const float A  = qb0 ? act : v1;
            const float Bx = qb0 ? v2 : v3;
            const float fv = qb1 ? Bx : A;    // sigm(f)
            const float ov = qb1 ? A : Bx;    // sigm(o)

            c = fmaf(fv, c, P1);
            const float tc = fmaf(2.f, frcp(1.f + exp2f(c * -LOG2E2)), -1.f);  // tanh(c)
            const float hn = ov * tc;

            if (e == 0) smem[HIST0 + ph * 64 + j] = hn;   // hist[ph] = h(t)

            if (ph == 8 && pfv) {   // land next-chunk stage (vmcnt wait is
                if (!FIRST) {       // data-dependent, inserted here only)
                    *(float2*)&smem[XC0 + (1 - buf) * 1024 + srow * 64 + sc2] = pf2;
                } else if (tid < 24) {
                    float tmp[4] = {pf4.x, pf4.y, pf4.z, pf4.w};
#pragma unroll
                    for (int m = 0; m < 4; ++m) {
                        int idx = tid * 4 + m;
                        smem[XC0 + (1 - buf) * 1024 + (idx / 6) * 64 + (idx % 6)] = tmp[m];
                    }
                }
            }

            if (ph < CH - 1) lds_barrier();   // LDS-only sync: no vmcnt drain
            else             __syncthreads(); // chunk boundary: full drain
        }

        // coalesced flush: hist rows 0..15 -> seq rows ck*16..+15
        if (!LAST) {
            float2 hv = *(const float2*)&smem[HIST0 + srow * 64 + sc2];
            *(float2*)sp = hv;
            __syncthreads();   // protect hist[0] from next chunk's ph0 write
        } else if (ck == NCH - 1) {
            if (srow == 15) {
                float2 hv = *(const float2*)&smem[HIST0 + 15 * 64 + sc2];
                *(float2*)sp = hv;
            }
        }
        sp += (size_t)CH * BB * HH;
        if (!FIRST) gp += (size_t)CH * BB * HH;
        else        xp += 96;
    }
}

// out[b] = fc_b + sum_j relu(h[T-1][b][j]) * fc_w[j]
__global__ __launch_bounds__(256)
void fc_kernel(const float* __restrict__ seq, const float* __restrict__ fcw,
               const float* __restrict__ fcb, float* __restrict__ out)
{
    __shared__ float w[HH];
    const int tid = threadIdx.x;
    if (tid < HH) w[tid] = fcw[tid];
    __syncthreads();
    const float* h = &seq[((size_t)(TT - 1) * BB + tid) * HH];
    float s = fcb[0];
#pragma unroll
    for (int jj = 0; jj < HH; ++jj)
        s = fmaf(fmaxf(h[jj], 0.f), w[jj], s);
    out[tid] = s;
}

extern "C" void kernel_launch(void* const* d_in, const int* in_sizes, int n_in,
                              void* d_out, int out_size, void* d_ws, size_t ws_size,
                              hipStream_t stream) {
    const float* x    = (const float*)d_in[0];  // [B][T][6]
    const float* Wih0 = (const float*)d_in[1];  // [256][6]
    const float* WihR = (const float*)d_in[2];  // [3][256][64]
    const float* Whh  = (const float*)d_in[3];  // [4][256][64]
    const float* bih  = (const float*)d_in[4];  // [4][256]
    const float* bhh  = (const float*)d_in[5];  // [4][256]
    const float* fcw  = (const float*)d_in[6];  // [1][64]
    const float* fcb  = (const float*)d_in[7];  // [1]
    float* out = (float*)d_out;
    float* seq = (float*)d_ws;                  // [T][B][64] fp32 = 268 MB

    dim3 grid(BB), block(NT);

    lstm_layer<true, false><<<grid, block, 0, stream>>>(x, Wih0, Whh, bih, bhh, seq);
    lstm_layer<false, false><<<grid, block, 0, stream>>>(
        nullptr, WihR + (size_t)0 * 256 * HH, Whh + (size_t)1 * 256 * HH,
        bih + 256, bhh + 256, seq);
    lstm_layer<false, false><<<grid, block, 0, stream>>>(
        nullptr, WihR + (size_t)1 * 256 * HH, Whh + (size_t)2 * 256 * HH,
        bih + 2 * 256, bhh + 2 * 256, seq);
    lstm_layer<false, true><<<grid, block, 0, stream>>>(
        nullptr, WihR + (size_t)2 * 256 * HH, Whh + (size_t)3 * 256 * HH,
        bih + 3 * 256, bhh + 3 * 256, seq);

    fc_kernel<<<dim3(1), dim3(256), 0, stream>>>(seq, fcw, fcb, out);
}

// Round 9
// 6567.870 us; speedup vs baseline: 1.1179x; 1.1032x over previous
//
#include <hip/hip_runtime.h>
#include <cstddef>

#define BB 256   // batch
#define TT 4096  // time steps
#define HH 64    // hidden
#define NT 512   // threads: 64 units x 8 K-slices
#define CH 16    // chunk depth (steps)
#define NCH (TT / CH)

// smem float layout (bank-tuned):
//   [8, 2056)    xc: 2 bufs x 16 rows x 64 cols  (base ≡ 8 mod 32)
//   [2064, 3088) hist ring: 16 rows x 64         (base ≡ 16 mod 32)
#define XC0   8
#define HIST0 2064
#define SMEMF 3092

#define LOG2E  1.442695041f
#define LOG2E2 2.885390082f

// produced-chunk counters for layer outputs 0..2 (layer l+1 polls row l).
// Device global -> no assumptions about ws_size; zeroed each launch.
__device__ int g_flags[3 * BB];

__global__ void zero_flags_kernel() { g_flags[threadIdx.x] = 0; }

__device__ __forceinline__ float dpp_xor1(float x) {  // lane ^= 1 (quad_perm)
    return __int_as_float(__builtin_amdgcn_mov_dpp(__float_as_int(x), 0xB1, 0xF, 0xF, true));
}
__device__ __forceinline__ float dpp_xor2(float x) {  // lane ^= 2 (quad_perm)
    return __int_as_float(__builtin_amdgcn_mov_dpp(__float_as_int(x), 0x4E, 0xF, 0xF, true));
}
__device__ __forceinline__ float swz_xor4(float x) {  // lane ^= 4 (ds_swizzle)
    return __int_as_float(__builtin_amdgcn_ds_swizzle(__float_as_int(x), 0x101F));
}
__device__ __forceinline__ float frcp(float x) { return __builtin_amdgcn_rcpf(x); }

// Raw workgroup barrier: LDS-ordering only (no vmcnt drain).
__device__ __forceinline__ void lds_barrier() {
    asm volatile("s_waitcnt lgkmcnt(0)\n\ts_barrier" ::: "memory");
}

// 4-layer pipelined LSTM. Grid = 1024 blocks: block (l = bid>>8, b = bid&255).
// At 88 VGPR (waves_per_eu(4,4)) two blocks co-reside per CU -> two
// INDEPENDENT barrier domains interleave on each SIMD, filling the per-step
// serial-chain stalls that flat-lined R3-R7. Layer l+1 consumes layer l's
// seq chunks via device-scope acquire/release flags; seq is updated in-place
// (each block stages chunk ck into LDS before overwriting it at flush).
// Producers never wait on consumers -> no producer-side deadlock; R8 run
// confirmed the dispatch order schedules producers first.
__global__ __attribute__((amdgpu_flat_work_group_size(NT, NT), amdgpu_waves_per_eu(4, 4)))
void lstm_pipe(const float* __restrict__ xg,    // x [B][T][6]
               const float* __restrict__ Wih0,  // [256][6]
               const float* __restrict__ WihR,  // [3][256][64]
               const float* __restrict__ Whh4,  // [4][256][64]
               const float* __restrict__ bih4,  // [4][256]
               const float* __restrict__ bhh4,  // [4][256]
               float* __restrict__ seq)         // [T][B][64] in-place
{
    const int bid = blockIdx.x;
    const int l   = bid >> 8;
    const int b   = bid & (BB - 1);
    const bool FIRST = (l == 0);
    const bool LAST  = (l == 3);
    const float* Wih = FIRST ? Wih0 : (WihR + (size_t)(l - 1) * 256 * HH);
    const float* Whh = Whh4 + (size_t)l * 256 * HH;
    const float* bih = bih4 + l * 256;
    const float* bhh = bhh4 + l * 256;
    int* const fin  = &g_flags[(l - 1) * BB + b];  // dereferenced only if l>0
    int* const fout = &g_flags[l * BB + b];        // dereferenced only if l<3

    const int tid = threadIdx.x;
    const int j   = tid >> 3;
    const int e   = tid & 7;
    const int eq  = e & 3;
    const int kb  = e >> 2;
    const bool qb0 = (e & 1) != 0;
    const bool qb1 = (e & 2) != 0;

    __shared__ __align__(16) float smem[SMEMF];

    // ---- weights: 16 named float4 = 64 floats ----
    float4 w00, w01, w02, w03, w10, w11, w12, w13;
    float4 w20, w21, w22, w23, w30, w31, w32, w33;
    {
        const float4 z = make_float4(0.f, 0.f, 0.f, 0.f);
        w00 = z; w01 = z; w02 = z; w03 = z; w10 = z; w11 = z; w12 = z; w13 = z;
        w20 = z; w21 = z; w22 = z; w23 = z; w30 = z; w31 = z; w32 = z; w33 = z;
    }
    if (!FIRST || kb == 0) {
        const float* Wp = kb ? Wih : Whh;
#define LDW(q, KS) { const float4* rp = (const float4*)(Wp + ((q << 6) + j) * HH + eq * 16); \
        float4 v0 = rp[0], v1 = rp[1], v2 = rp[2], v3 = rp[3]; \
        (w##q##0) = make_float4(v0.x*KS, v0.y*KS, v0.z*KS, v0.w*KS); \
        (w##q##1) = make_float4(v1.x*KS, v1.y*KS, v1.z*KS, v1.w*KS); \
        (w##q##2) = make_float4(v2.x*KS, v2.y*KS, v2.z*KS, v2.w*KS); \
        (w##q##3) = make_float4(v3.x*KS, v3.y*KS, v3.z*KS, v3.w*KS); }
        LDW(0, LOG2E) LDW(1, LOG2E) LDW(2, LOG2E2) LDW(3, LOG2E)
#undef LDW
    } else if (e == 4) {  // layer 0, x-slice lane: 6-wide rows zero-padded
#define LDW6(q, KS) { const float* rp = Wih + ((q << 6) + j) * 6; \
        (w##q##0) = make_float4(rp[0]*KS, rp[1]*KS, rp[2]*KS, rp[3]*KS); \
        (w##q##1).x = rp[4]*KS; (w##q##1).y = rp[5]*KS; }
        LDW6(0, LOG2E) LDW6(1, LOG2E) LDW6(2, LOG2E2) LDW6(3, LOG2E)
#undef LDW6
    }

    // per-gate bias * ksc / 8 (8-lane reduce tree sums 8 copies -> full bias)
    const float b0 = (bih[0 * 64 + j] + bhh[0 * 64 + j]) * (LOG2E * 0.125f);
    const float b1 = (bih[1 * 64 + j] + bhh[1 * 64 + j]) * (LOG2E * 0.125f);
    const float b2 = (bih[2 * 64 + j] + bhh[2 * 64 + j]) * (LOG2E2 * 0.125f);
    const float b3 = (bih[3 * 64 + j] + bhh[3 * 64 + j]) * (LOG2E * 0.125f);

    const float sg = (eq == 2) ? 2.f : 1.f;   // outer: tanh = 2*s-1
    const float og = (eq == 2) ? -1.f : 0.f;

    // zero hist; layer 0 also zeros xc (cols >=6 stay 0 forever)
    if (FIRST) { for (int i = tid; i < SMEMF; i += NT) smem[i] = 0.f; }
    else       { for (int i = HIST0 + tid; i < SMEMF; i += NT) smem[i] = 0.f; }
    __syncthreads();

    // ---- wait for producer's chunk 0, then stage it ----
    if (!FIRST) {
        if (tid == 0) {
            while (__hip_atomic_load(fin, __ATOMIC_ACQUIRE, __HIP_MEMORY_SCOPE_AGENT) < 1)
                __builtin_amdgcn_s_sleep(8);
        }
        __syncthreads();
    }

    const int srow = tid >> 5;           // 0..15
    const int sc2  = (tid & 31) << 1;    // even col
    const float* gp = nullptr;
    const float* xp = nullptr;
    if (!FIRST) {
        gp = seq + ((size_t)srow * BB + b) * HH + sc2;
        float2 v = *(const float2*)gp;
        *(float2*)&smem[XC0 + srow * 64 + sc2] = v;
        gp += (size_t)CH * BB * HH;      // -> chunk 1
    } else {
        xp = xg + (size_t)b * TT * 6 + tid * 4;
        if (tid < 24) {
            float4 v = *(const float4*)xp;
            float tmp[4] = {v.x, v.y, v.z, v.w};
#pragma unroll
            for (int m = 0; m < 4; ++m) {
                int idx = tid * 4 + m;
                smem[XC0 + (idx / 6) * 64 + (idx % 6)] = tmp[m];
            }
        }
        xp += 96;
    }
    float* sp = seq + ((size_t)srow * BB + b) * HH + sc2;   // flush ptr
    float c = 0.f;
    __syncthreads();

    float2 pf2 = make_float2(0.f, 0.f);
    float4 pf4 = make_float4(0.f, 0.f, 0.f, 0.f);

    for (int ck = 0; ck < NCH; ++ck) {
        const int buf = ck & 1;
        const float* vb  = kb ? (smem + XC0 + buf * 1024 + eq * 16)
                              : (smem + HIST0 - 64 + eq * 16);
        const float* vb0 = kb ? vb : (smem + HIST0 + 15 * 64 + eq * 16);
        const bool pfv = (ck + 1 < NCH);

        // before prefetching chunk ck+1, ensure producer published it
        if (!FIRST && pfv) {
            if (tid == 0) {
                while (__hip_atomic_load(fin, __ATOMIC_ACQUIRE, __HIP_MEMORY_SCOPE_AGENT) < ck + 2)
                    __builtin_amdgcn_s_sleep(8);
            }
            __syncthreads();
        }

#pragma unroll
        for (int ph = 0; ph < CH; ++ph) {
            if (ph == 0 && pfv) {   // issue next-chunk global loads
                if (!FIRST) pf2 = *(const float2*)gp;
                else if (tid < 24) pf4 = *(const float4*)xp;
            }

            const float4* vp = (const float4*)((ph == 0) ? vb0 : (vb + ph * 64));
            const float4 vv0 = vp[0], vv1 = vp[1], vv2 = vp[2], vv3 = vp[3];

            // gate chains: first ops fold bias/8 (fma) and replace zero-init
#define GATE(q, bq, aq) { \
            float pa = fmaf((w##q##0).x, vv0.x, bq); \
            pa = fmaf((w##q##0).y, vv0.y, pa); \
            pa = fmaf((w##q##0).z, vv0.z, pa); \
            pa = fmaf((w##q##0).w, vv0.w, pa); \
            float pb = (w##q##1).x * vv1.x; \
            pb = fmaf((w##q##1).y, vv1.y, pb); \
            pb = fmaf((w##q##1).z, vv1.z, pb); \
            pb = fmaf((w##q##1).w, vv1.w, pb); \
            pa = fmaf((w##q##2).x, vv2.x, pa); \
            pa = fmaf((w##q##2).y, vv2.y, pa); \
            pa = fmaf((w##q##2).z, vv2.z, pa); \
            pa = fmaf((w##q##2).w, vv2.w, pa); \
            pb = fmaf((w##q##3).x, vv3.x, pb); \
            pb = fmaf((w##q##3).y, vv3.y, pb); \
            pb = fmaf((w##q##3).z, vv3.z, pb); \
            pb = fmaf((w##q##3).w, vv3.w, pb); \
            aq = pa + pb; }
            float a0, a1, a2, a3;
            GATE(0, b0, a0) GATE(1, b1, a1) GATE(2, b2, a2) GATE(3, b3, a3)
#undef GATE

            // reduce-scatter over e: lane ends with gate q = e&3
            const float s0 = dpp_xor1(a0), s1 = dpp_xor1(a1);
            const float s2 = dpp_xor1(a2), s3 = dpp_xor1(a3);
            const float k0 = qb0 ? (a1 + s1) : (a0 + s0);
            const float k2 = qb0 ? (a3 + s3) : (a2 + s2);
            const float u0 = dpp_xor2(k0), u2 = dpp_xor2(k2);
            float g = qb1 ? (k2 + u2) : (k0 + u0);
            g += swz_xor4(g);   // known-good xor4 (ds_swizzle); DPP ror select
                                // was R8's bug (direction swapped)

            // act: sigm via native exp2 (log2e pre-folded into w/b)
            const float act = fmaf(sg, frcp(1.f + exp2f(-g)), og);

            // gather acts, replicated c/h update
            const float v1 = dpp_xor1(act);
            const float v2 = dpp_xor2(act);
            const float v3 = dpp_xor2(v1);
            const float px = act * v2, py = v1 * v3;
            const float P1 = qb0 ? py : px;   // sigm(i)*tanh(g)
            const float A  = qb0 ? act : v1;
            const float Bx = qb0 ? v2 : v3;
            const float fv = qb1 ? Bx : A;    // sigm(f)
            const float ov = qb1 ? A : Bx;    // sigm(o)

            c = fmaf(fv, c, P1);
            const float tc = fmaf(2.f, frcp(1.f + exp2f(c * -LOG2E2)), -1.f);  // tanh(c)
            const float hn = ov * tc;

            if (e == 0) smem[HIST0 + ph * 64 + j] = hn;   // hist[ph] = h(t)

            if (ph == 8 && pfv) {   // land next-chunk stage
                if (!FIRST) {
                    *(float2*)&smem[XC0 + (1 - buf) * 1024 + srow * 64 + sc2] = pf2;
                } else if (tid < 24) {
                    float tmp[4] = {pf4.x, pf4.y, pf4.z, pf4.w};
#pragma unroll
                    for (int m = 0; m < 4; ++m) {
                        int idx = tid * 4 + m;
                        smem[XC0 + (1 - buf) * 1024 + (idx / 6) * 64 + (idx % 6)] = tmp[m];
                    }
                }
            }

            if (ph < CH - 1) lds_barrier();   // LDS-only sync
            else             __syncthreads(); // chunk boundary
        }

        // flush hist rows 0..15 -> seq rows ck*16..+15, then publish chunk
        if (!LAST) {
            float2 hv = *(const float2*)&smem[HIST0 + srow * 64 + sc2];
            *(float2*)sp = hv;
            __syncthreads();   // drains each thread's stores + protects hist[0]
            if (tid == 0)
                __hip_atomic_store(fout, ck + 1, __ATOMIC_RELEASE, __HIP_MEMORY_SCOPE_AGENT);
        } else if (ck == NCH - 1) {
            if (srow == 15) {
                float2 hv = *(const float2*)&smem[HIST0 + 15 * 64 + sc2];
                *(float2*)sp = hv;
            }
        }
        sp += (size_t)CH * BB * HH;
        if (!FIRST) gp += (size_t)CH * BB * HH;
        else        xp += 96;
    }
}

// out[b] = fc_b + sum_j relu(h[T-1][b][j]) * fc_w[j]
__global__ __launch_bounds__(256)
void fc_kernel(const float* __restrict__ seq, const float* __restrict__ fcw,
               const float* __restrict__ fcb, float* __restrict__ out)
{
    __shared__ float w[HH];
    const int tid = threadIdx.x;
    if (tid < HH) w[tid] = fcw[tid];
    __syncthreads();
    const float* h = &seq[((size_t)(TT - 1) * BB + tid) * HH];
    float s = fcb[0];
#pragma unroll
    for (int jj = 0; jj < HH; ++jj)
        s = fmaf(fmaxf(h[jj], 0.f), w[jj], s);
    out[tid] = s;
}

extern "C" void kernel_launch(void* const* d_in, const int* in_sizes, int n_in,
                              void* d_out, int out_size, void* d_ws, size_t ws_size,
                              hipStream_t stream) {
    const float* x    = (const float*)d_in[0];  // [B][T][6]
    const float* Wih0 = (const float*)d_in[1];  // [256][6]
    const float* WihR = (const float*)d_in[2];  // [3][256][64]
    const float* Whh  = (const float*)d_in[3];  // [4][256][64]
    const float* bih  = (const float*)d_in[4];  // [4][256]
    const float* bhh  = (const float*)d_in[5];  // [4][256]
    const float* fcw  = (const float*)d_in[6];  // [1][64]
    const float* fcb  = (const float*)d_in[7];  // [1]
    float* out = (float*)d_out;
    float* seq = (float*)d_ws;                  // [T][B][64] fp32 = 268 MB

    zero_flags_kernel<<<dim3(1), dim3(3 * BB), 0, stream>>>();
    lstm_pipe<<<dim3(4 * BB), dim3(NT), 0, stream>>>(x, Wih0, WihR, Whh, bih, bhh, seq);
    fc_kernel<<<dim3(1), dim3(256), 0, stream>>>(seq, fcw, fcb, out);
}